// Round 1
// baseline (198.619 us; speedup 1.0000x reference)
//
#include <hip/hip_runtime.h>
#include <hip/hip_bf16.h>
#include <hip/hip_fp16.h>
#include <cstdint>

#define EMBED 256
#define GPS 8        // groups
#define NCAM 6
#define NLVL 4
#define NPT 13
#define NANC 900
#define NSAMP (NCAM*NLVL*NPT)   // 312
#define NWCOL (GPS*NSAMP)       // 2496
#define MPAD 928                // 29 tiles of 32 rows
#define WSTRIDE 328             // LDS stride for [g][s] weights (conflict-free)
#define MAXENT 352              // pad32 (<=320) + overrun slots

// contiguous fp8 feature buffer: BYTE offsets per level (1 B/elem)
#define FMOFF0 0
#define FMOFF1 17301504            // 6*11264*256
#define FMOFF2 21626880            // +6*2816*256
#define FMOFF3 22708224            // +6*704*256
#define TALL_BYTES 22978560        // +6*176*256

typedef __attribute__((ext_vector_type(8))) short bf16x8;
typedef __attribute__((ext_vector_type(16))) float f32x16;
typedef __attribute__((ext_vector_type(2))) float v2f;

__device__ __forceinline__ ushort bf16bits(float x) {
    __hip_bfloat16 h = __float2bfloat16(x);
    return *reinterpret_cast<ushort*>(&h);
}

// ---------------- K1: fused prep (unchanged) ---------------------------------
__global__ __launch_bounds__(256) void k_prep(
        const float* __restrict__ fm0, const float* __restrict__ fm1,
        const float* __restrict__ fm2, const float* __restrict__ fm3,
        unsigned char* __restrict__ t0, unsigned char* __restrict__ t1,
        unsigned char* __restrict__ t2, unsigned char* __restrict__ t3,
        const float* __restrict__ wlin, __hip_bfloat16* __restrict__ wt,
        const float* __restrict__ inst, const float* __restrict__ anch,
        __hip_bfloat16* __restrict__ featB,
        const float* __restrict__ kp, const float* __restrict__ proj,
        float* __restrict__ pxy) {
    __shared__ ushort lds2[128 * 64];     // 16 KiB
    int b = blockIdx.x;
    int t = threadIdx.x;
    if (b < 1404) {
        const float* in; unsigned char* outp; int HW, chunks, lb;
        if (b < 1056)      { in = fm0; outp = t0; HW = 11264; chunks = 176; lb = b; }
        else if (b < 1320) { in = fm1; outp = t1; HW = 2816;  chunks = 44;  lb = b - 1056; }
        else if (b < 1386) { in = fm2; outp = t2; HW = 704;   chunks = 11;  lb = b - 1320; }
        else               { in = fm3; outp = t3; HW = 176;   chunks = 3;   lb = b - 1386; }
        int c = lb / chunks;
        int hw0 = (lb - c * chunks) * 64;
        int q = t & 15, eg = t >> 4;
        bool vld = (hw0 + q * 4 + 3) < HW;
        const float* srcq = in + (size_t)c * EMBED * HW + hw0 + q * 4;
        float4 vals[16];
        #pragma unroll
        for (int r = 0; r < 16; r++) {
            int e = 2 * eg + (r & 1) + 32 * (r >> 1);
            vals[r] = vld ? *(const float4*)(srcq + (size_t)e * HW)
                          : make_float4(0.f, 0.f, 0.f, 0.f);
        }
        #pragma unroll
        for (int rp = 0; rp < 8; rp++) {
            int ep = eg + 16 * rp;
            int s2 = (ep >> 1) & 62;
            float4 va = vals[2 * rp], vb = vals[2 * rp + 1];
            uint p0 = (uint)__builtin_amdgcn_cvt_pk_fp8_f32(va.x, vb.x, 0, false) & 0xffff;
            uint p1 = (uint)__builtin_amdgcn_cvt_pk_fp8_f32(va.y, vb.y, 0, false) & 0xffff;
            uint p2 = (uint)__builtin_amdgcn_cvt_pk_fp8_f32(va.z, vb.z, 0, false) & 0xffff;
            uint p3 = (uint)__builtin_amdgcn_cvt_pk_fp8_f32(va.w, vb.w, 0, false) & 0xffff;
            int col01 = (q * 4) ^ s2;
            int col23 = (q * 4 + 2) ^ s2;
            *reinterpret_cast<uint*>(&lds2[ep * 64 + col01]) = p0 | (p1 << 16);
            *reinterpret_cast<uint*>(&lds2[ep * 64 + col23]) = p2 | (p3 << 16);
        }
        __syncthreads();
        ushort* outb = reinterpret_cast<ushort*>(outp) + ((size_t)c * HW + hw0) * 128;
        #pragma unroll
        for (int r = 0; r < 8; r++) {
            int flat = r * 2048 + t * 8;          // byte index in chunk
            int hw = flat >> 8;
            int ep0 = (flat & 255) >> 1;          // 4*(t&31)
            if (hw0 + hw < HW) {
                ushort4 u;
                #pragma unroll
                for (int j = 0; j < 4; j++) {
                    int ep = ep0 + j;
                    int s2 = (ep >> 1) & 62;
                    u[j] = lds2[ep * 64 + (hw ^ s2)];
                }
                *reinterpret_cast<ushort4*>(outb + flat / 2) = u;
            }
        }
    } else if (b < 1560) {
        int b1 = b - 1404;
        int kt = b1 / 39, nt = b1 - kt * 39;
        int k0 = kt * 64, n0 = nt * 64;
        int grp = t >> 6, nn = t & 63;
        #pragma unroll
        for (int r = 0; r < 16; r++) {
            int kk = grp * 16 + r;
            lds2[kk * 65 + nn] = bf16bits(wlin[(size_t)(k0 + kk) * NWCOL + n0 + nn]);
        }
        __syncthreads();
        ushort* wtb = reinterpret_cast<ushort*>(wt);
        int kk2 = t & 63;
        #pragma unroll
        for (int r = 0; r < 16; r++) {
            int nn2 = grp * 16 + r;
            wtb[(size_t)(n0 + nn2) * EMBED + k0 + kk2] = lds2[kk2 * 65 + nn2];
        }
    } else if (b < 1785) {
        int base = (b - 1560) * 1024 + t * 4;
        float4 a = *(const float4*)&inst[base];
        float4 c = *(const float4*)&anch[base];
        ushort4 r;
        r.x = bf16bits(a.x + c.x); r.y = bf16bits(a.y + c.y);
        r.z = bf16bits(a.z + c.z); r.w = bf16bits(a.w + c.w);
        *reinterpret_cast<ushort4*>(reinterpret_cast<ushort*>(featB) + base) = r;
    } else if (b < 1792) {
        int base = 900 * EMBED + (b - 1785) * 1024 + t * 4;
        ushort4 z; z.x = z.y = z.z = z.w = 0;
        *reinterpret_cast<ushort4*>(reinterpret_cast<ushort*>(featB) + base) = z;
    } else {
        int i = (b - 1792) * 256 + t;
        if (i < NANC * NCAM * NPT) {
            int a = i / (NCAM * NPT);
            int r = i - a * (NCAM * NPT);
            int c = r / NPT;
            int p = r - c * NPT;
            const float* M = proj + c * 16;
            const float* k3 = kp + ((size_t)a * NPT + p) * 3;
            float kx = k3[0], ky = k3[1], kz = k3[2];
            float X = M[0] * kx + M[1] * ky + M[2] * kz + M[3];
            float Y = M[4] * kx + M[5] * ky + M[6] * kz + M[7];
            float Z = M[8] * kx + M[9] * ky + M[10] * kz + M[11];
            float invz = 1.f / fmaxf(Z, 1e-5f);
            pxy[(size_t)i * 2 + 0] = X * invz;
            pxy[(size_t)i * 2 + 1] = Y * invz;
        }
    }
}

// ---------------- K2: logits GEMM via MFMA bf16 (unchanged) ------------------
#define MT 29
#define NT 78
__global__ __launch_bounds__(256) void k_gemm(const __hip_bfloat16* __restrict__ featB,
                                              const __hip_bfloat16* __restrict__ wt,
                                              const float* __restrict__ blin,
                                              float* __restrict__ logits) {
    int wv = threadIdx.x >> 6, lane = threadIdx.x & 63;
    int idx = blockIdx.x * 4 + wv;
    if (idx >= MT * NT) return;
    int mt = idx % MT, nt = idx / MT;
    int m0 = mt * 32, n0 = nt * 32;
    int l31 = lane & 31;
    int khalf = (lane >> 5) * 8;
    const short* ap = reinterpret_cast<const short*>(featB) + (size_t)(m0 + l31) * EMBED + khalf;
    const short* bp = reinterpret_cast<const short*>(wt)    + (size_t)(n0 + l31) * EMBED + khalf;
    f32x16 acc = {};
    #pragma unroll 8
    for (int ki = 0; ki < 16; ki++) {
        bf16x8 a = *reinterpret_cast<const bf16x8*>(ap + ki * 16);
        bf16x8 bb = *reinterpret_cast<const bf16x8*>(bp + ki * 16);
        acc = __builtin_amdgcn_mfma_f32_32x32x16_bf16(a, bb, acc, 0, 0, 0);
    }
    float bias = blin[n0 + l31];
    int colg = n0 + l31;
    #pragma unroll
    for (int r = 0; r < 16; r++) {
        int row = (r & 3) + 8 * (r >> 2) + 4 * (lane >> 5);
        int grow = m0 + row;
        if (grow < NANC)
            logits[(size_t)grow * NWCOL + colg] = acc[r] + bias;
    }
}

// ---------------- K3: softmax + compacted fp8 gather -------------------------
// Restructured gather: each 32-lane half-wave owns one entry; a lane covers 8
// channels (uint2 = dwordx2 per corner). Per entry-pair this halves global-load
// instructions (8->4), halves addr calc + wT LDS reads, and doubles entries in
// flight per wave (depth-2 over pairs = 4 entries / 16 loads outstanding).
// Softmax is 2-pass: wT holds exp(x-m); 1/sum folded into epilogue via rsS.
__global__ __launch_bounds__(512) void k_aggregate(const unsigned char* __restrict__ tAll,
                                                   const float* __restrict__ logits,
                                                   const float* __restrict__ pxy,
                                                   const float* __restrict__ wout,
                                                   const float* __restrict__ bout,
                                                   const float* __restrict__ inst,
                                                   float* __restrict__ out) {
    __shared__ float wT[GPS * WSTRIDE];    // 10496 B
    __shared__ float xyS[NCAM * NPT * 2];  // 624 B
    __shared__ float redS[8][EMBED];       // 8192 B
    __shared__ float pS[EMBED];            // 1024 B
    __shared__ float rsS[GPS];             // 32 B
    __shared__ int4  eOff[MAXENT];         // 5632 B
    __shared__ float4 eW[MAXENT];          // 5632 B
    __shared__ int   eS[MAXENT];           // 1408 B
    __shared__ int   cntS;
    int a = blockIdx.x;
    int tid = threadIdx.x;
    int wave = tid >> 6;
    int lane = tid & 63;
    if (tid == 0) cntS = 0;
    for (int j = tid; j < NWCOL; j += 512)
        wT[(j & 7) * WSTRIDE + (j >> 3)] = logits[(size_t)a * NWCOL + j];
    for (int j = tid; j < NCAM * NPT * 2; j += 512)
        xyS[j] = pxy[(size_t)a * NCAM * NPT * 2 + j];
    __syncthreads();
    // ---- softmax numerator: wave g owns group g; wT <- exp(x - m) ----
    {
        int g = wave;
        float m = -1e30f;
        for (int s = lane; s < NSAMP; s += 64) m = fmaxf(m, wT[g * WSTRIDE + s]);
        #pragma unroll
        for (int off = 32; off; off >>= 1) m = fmaxf(m, __shfl_xor(m, off));
        float ssum = 0.f;
        for (int s = lane; s < NSAMP; s += 64) {
            float e = __expf(wT[g * WSTRIDE + s] - m);
            wT[g * WSTRIDE + s] = e;
            ssum += e;
        }
        #pragma unroll
        for (int off = 32; off; off >>= 1) ssum += __shfl_xor(ssum, off);
        if (lane == 0) rsS[g] = 1.f / ssum;
    }
    // ---- sample precompute + compaction ----
    {
        bool valid = false; int4 o4; float4 w4;
        if (tid < NSAMP) {
            int c = tid / 52, rem = tid - c * 52;
            int l = rem / 13, p = rem - l * 13;
            float X = xyS[(c * NPT + p) * 2], Y = xyS[(c * NPT + p) * 2 + 1];
            int Wl = 176 >> l, Hl = 64 >> l;
            float scale = 0.25f / (float)(1 << l);
            float gx = fmaf(X, scale, -0.5f);
            float gy = fmaf(Y, scale, -0.5f);
            float x0f = floorf(gx), y0f = floorf(gy);
            float fx = gx - x0f, fy = gy - y0f;
            int x0 = (int)x0f, y0 = (int)y0f;
            int x1 = x0 + 1, y1 = y0 + 1;
            bool vx0 = (x0 >= 0) && (x0 < Wl);
            bool vx1 = (x1 >= 0) && (x1 < Wl);
            bool vy0 = (y0 >= 0) && (y0 < Hl);
            bool vy1 = (y1 >= 0) && (y1 < Hl);
            w4.x = (vx0 && vy0) ? (1.f - fx) * (1.f - fy) : 0.f;
            w4.y = (vx1 && vy0) ? fx * (1.f - fy) : 0.f;
            w4.z = (vx0 && vy1) ? (1.f - fx) * fy : 0.f;
            w4.w = (vx1 && vy1) ? fx * fy : 0.f;
            if (w4.x + w4.y + w4.z + w4.w > 0.f) {
                valid = true;
                int xc0 = min(max(x0, 0), Wl - 1), xc1 = min(max(x1, 0), Wl - 1);
                int yc0 = min(max(y0, 0), Hl - 1), yc1 = min(max(y1, 0), Hl - 1);
                const int lvlBase[4] = { FMOFF0, FMOFF1, FMOFF2, FMOFF3 };
                int cb = lvlBase[l] + c * (Wl * Hl) * EMBED;
                o4.x = cb + (yc0 * Wl + xc0) * EMBED;
                o4.y = cb + (yc0 * Wl + xc1) * EMBED;
                o4.z = cb + (yc1 * Wl + xc0) * EMBED;
                o4.w = cb + (yc1 * Wl + xc1) * EMBED;
            }
        }
        unsigned long long mask = __ballot(valid);
        int prefix = __popcll(mask & ((1ull << lane) - 1ull));
        int wcount = __popcll(mask);
        int basev = 0;
        if (lane == 0 && wcount) basev = atomicAdd(&cntS, wcount);
        basev = __shfl(basev, 0);
        if (valid) {
            int pos = basev + prefix;
            eOff[pos] = o4; eW[pos] = w4; eS[pos] = tid;
        }
    }
    __syncthreads();
    int cnt = cntS;
    int cnt_pad = (cnt + 31) & ~31;       // multiple of 32 -> steps even
    for (int j = cnt + tid; j < cnt_pad; j += 512) {
        eOff[j] = make_int4(0, 0, 0, 0);
        eW[j] = make_float4(0.f, 0.f, 0.f, 0.f);
        eS[j] = 0;
    }
    __syncthreads();
    // ---- phase B: half-wave dual-entry pipelined fp8 gather ----
    int half = lane >> 5;
    int hl = lane & 31;
    int ch0 = hl * 8;                     // byte offset of this lane's 8 channels
    int g = hl >> 2;                      // group of channels [ch0, ch0+8)
    float acc0 = 0.f, acc1 = 0.f, acc2 = 0.f, acc3 = 0.f;
    float acc4 = 0.f, acc5 = 0.f, acc6 = 0.f, acc7 = 0.f;
    auto consume = [&](const float4& w, int sIdx,
                       uint2 c0, uint2 c1, uint2 c2, uint2 c3) {
        float wg = wT[g * WSTRIDE + sIdx];
        float w0 = wg * w.x, w1 = wg * w.y, w2 = wg * w.z, w3 = wg * w.w;
        v2f p;
        p = __builtin_amdgcn_cvt_pk_f32_fp8(c0.x, false); acc0 = fmaf(w0, p.x, acc0); acc1 = fmaf(w0, p.y, acc1);
        p = __builtin_amdgcn_cvt_pk_f32_fp8(c0.x, true);  acc2 = fmaf(w0, p.x, acc2); acc3 = fmaf(w0, p.y, acc3);
        p = __builtin_amdgcn_cvt_pk_f32_fp8(c0.y, false); acc4 = fmaf(w0, p.x, acc4); acc5 = fmaf(w0, p.y, acc5);
        p = __builtin_amdgcn_cvt_pk_f32_fp8(c0.y, true);  acc6 = fmaf(w0, p.x, acc6); acc7 = fmaf(w0, p.y, acc7);
        p = __builtin_amdgcn_cvt_pk_f32_fp8(c1.x, false); acc0 = fmaf(w1, p.x, acc0); acc1 = fmaf(w1, p.y, acc1);
        p = __builtin_amdgcn_cvt_pk_f32_fp8(c1.x, true);  acc2 = fmaf(w1, p.x, acc2); acc3 = fmaf(w1, p.y, acc3);
        p = __builtin_amdgcn_cvt_pk_f32_fp8(c1.y, false); acc4 = fmaf(w1, p.x, acc4); acc5 = fmaf(w1, p.y, acc5);
        p = __builtin_amdgcn_cvt_pk_f32_fp8(c1.y, true);  acc6 = fmaf(w1, p.x, acc6); acc7 = fmaf(w1, p.y, acc7);
        p = __builtin_amdgcn_cvt_pk_f32_fp8(c2.x, false); acc0 = fmaf(w2, p.x, acc0); acc1 = fmaf(w2, p.y, acc1);
        p = __builtin_amdgcn_cvt_pk_f32_fp8(c2.x, true);  acc2 = fmaf(w2, p.x, acc2); acc3 = fmaf(w2, p.y, acc3);
        p = __builtin_amdgcn_cvt_pk_f32_fp8(c2.y, false); acc4 = fmaf(w2, p.x, acc4); acc5 = fmaf(w2, p.y, acc5);
        p = __builtin_amdgcn_cvt_pk_f32_fp8(c2.y, true);  acc6 = fmaf(w2, p.x, acc6); acc7 = fmaf(w2, p.y, acc7);
        p = __builtin_amdgcn_cvt_pk_f32_fp8(c3.x, false); acc0 = fmaf(w3, p.x, acc0); acc1 = fmaf(w3, p.y, acc1);
        p = __builtin_amdgcn_cvt_pk_f32_fp8(c3.x, true);  acc2 = fmaf(w3, p.x, acc2); acc3 = fmaf(w3, p.y, acc3);
        p = __builtin_amdgcn_cvt_pk_f32_fp8(c3.y, false); acc4 = fmaf(w3, p.x, acc4); acc5 = fmaf(w3, p.y, acc5);
        p = __builtin_amdgcn_cvt_pk_f32_fp8(c3.y, true);  acc6 = fmaf(w3, p.x, acc6); acc7 = fmaf(w3, p.y, acc7);
    };
    int steps = cnt_pad >> 4;             // 16 entries consumed per step (8 waves x 2)
    if (steps > 0) {
        int ei = wave * 2 + half;
        int4 oA = eOff[ei]; float4 wA = eW[ei]; int sA = eS[ei];
        uint2 vA0 = *(const uint2*)(tAll + oA.x + ch0);
        uint2 vA1 = *(const uint2*)(tAll + oA.y + ch0);
        uint2 vA2 = *(const uint2*)(tAll + oA.z + ch0);
        uint2 vA3 = *(const uint2*)(tAll + oA.w + ch0);
        for (int it = 0; it < steps; it += 2) {
            int ej = ei + 16;
            int4 oB = eOff[ej]; float4 wB = eW[ej]; int sB = eS[ej];
            uint2 vB0 = *(const uint2*)(tAll + oB.x + ch0);
            uint2 vB1 = *(const uint2*)(tAll + oB.y + ch0);
            uint2 vB2 = *(const uint2*)(tAll + oB.z + ch0);
            uint2 vB3 = *(const uint2*)(tAll + oB.w + ch0);
            consume(wA, sA, vA0, vA1, vA2, vA3);
            ei = ej + 16;
            if (it + 2 < steps) {
                oA = eOff[ei]; wA = eW[ei]; sA = eS[ei];
                vA0 = *(const uint2*)(tAll + oA.x + ch0);
                vA1 = *(const uint2*)(tAll + oA.y + ch0);
                vA2 = *(const uint2*)(tAll + oA.z + ch0);
                vA3 = *(const uint2*)(tAll + oA.w + ch0);
            }
            consume(wB, sB, vB0, vB1, vB2, vB3);
        }
    }
    // combine the two half-waves (same channels, disjoint entries)
    acc0 += __shfl_xor(acc0, 32); acc1 += __shfl_xor(acc1, 32);
    acc2 += __shfl_xor(acc2, 32); acc3 += __shfl_xor(acc3, 32);
    acc4 += __shfl_xor(acc4, 32); acc5 += __shfl_xor(acc5, 32);
    acc6 += __shfl_xor(acc6, 32); acc7 += __shfl_xor(acc7, 32);
    if (half == 0) {
        redS[wave][ch0 + 0] = acc0; redS[wave][ch0 + 1] = acc1;
        redS[wave][ch0 + 2] = acc2; redS[wave][ch0 + 3] = acc3;
        redS[wave][ch0 + 4] = acc4; redS[wave][ch0 + 5] = acc5;
        redS[wave][ch0 + 6] = acc6; redS[wave][ch0 + 7] = acc7;
    }
    __syncthreads();
    // ---- epilogue: softmax denom rescale + fused @ w_out + b_out + inst ----
    int col = tid & 255;
    int kh = tid >> 8;
    if (kh == 0) {
        float s = redS[0][col] + redS[1][col] + redS[2][col] + redS[3][col]
                + redS[4][col] + redS[5][col] + redS[6][col] + redS[7][col];
        redS[0][col] = s * rsS[col >> 5];
    }
    __syncthreads();
    float acc = 0.f;
    int kbase = kh * 128;
    #pragma unroll 8
    for (int k = 0; k < 128; k++)
        acc = fmaf(redS[0][kbase + k], wout[(size_t)(kbase + k) * EMBED + col], acc);
    if (kh == 1) pS[col] = acc;
    __syncthreads();
    if (kh == 0)
        out[(size_t)a * EMBED + col] = acc + pS[col] + bout[col] + inst[(size_t)a * EMBED + col];
}

extern "C" void kernel_launch(void* const* d_in, const int* in_sizes, int n_in,
                              void* d_out, int out_size, void* d_ws, size_t ws_size,
                              hipStream_t stream) {
    const float* inst = (const float*)d_in[0];
    const float* anch = (const float*)d_in[1];
    const float* kp   = (const float*)d_in[2];
    const float* fm0  = (const float*)d_in[3];
    const float* fm1  = (const float*)d_in[4];
    const float* fm2  = (const float*)d_in[5];
    const float* fm3  = (const float*)d_in[6];
    const float* proj = (const float*)d_in[7];
    const float* wlin = (const float*)d_in[9];
    const float* blin = (const float*)d_in[10];
    const float* wout = (const float*)d_in[11];
    const float* bout = (const float*)d_in[12];
    float* out = (float*)d_out;

    char* ws = (char*)d_ws;
    size_t off = 0;
    auto alloc = [&](size_t bytes) -> void* {
        void* p = ws + off;
        off = (off + bytes + 255) & ~(size_t)255;
        return p;
    };
    unsigned char* tAll = (unsigned char*)alloc((size_t)TALL_BYTES);
    unsigned char* t0 = tAll + FMOFF0;
    unsigned char* t1 = tAll + FMOFF1;
    unsigned char* t2 = tAll + FMOFF2;
    unsigned char* t3 = tAll + FMOFF3;
    __hip_bfloat16* wt    = (__hip_bfloat16*)alloc((size_t)NWCOL * EMBED * 2);
    __hip_bfloat16* featB = (__hip_bfloat16*)alloc((size_t)MPAD * EMBED * 2);
    float* logits = (float*)alloc((size_t)NANC * NWCOL * 4);
    float* pxy    = (float*)alloc((size_t)NANC * NCAM * NPT * 2 * 4);

    k_prep<<<dim3(2067), 256, 0, stream>>>(fm0, fm1, fm2, fm3, t0, t1, t2, t3,
                                           wlin, wt, inst, anch, featB, kp, proj, pxy);
    k_gemm<<<dim3((MT * NT + 3) / 4), 256, 0, stream>>>(featB, wt, blin, logits);
    k_aggregate<<<dim3(NANC), 512, 0, stream>>>(tAll, logits, pxy,
                                                wout, bout, inst, out);
}

// Round 2
// 197.631 us; speedup vs baseline: 1.0050x; 1.0050x over previous
//
#include <hip/hip_runtime.h>
#include <hip/hip_bf16.h>
#include <hip/hip_fp16.h>
#include <cstdint>

#define EMBED 256
#define GPS 8        // groups
#define NCAM 6
#define NLVL 4
#define NPT 13
#define NANC 900
#define NSAMP (NCAM*NLVL*NPT)   // 312
#define NWCOL (GPS*NSAMP)       // 2496
#define MPAD 928                // 29 tiles of 32 rows
#define WSTRIDE 328             // LDS stride for [g][s] weights (conflict-free)
#define MAXENT 352              // pad32 (<=320) + overrun slots

// contiguous fp8 feature buffer: BYTE offsets per level (1 B/elem)
#define FMOFF0 0
#define FMOFF1 17301504            // 6*11264*256
#define FMOFF2 21626880            // +6*2816*256
#define FMOFF3 22708224            // +6*704*256
#define TALL_BYTES 22978560        // +6*176*256

typedef __attribute__((ext_vector_type(8))) short bf16x8;
typedef __attribute__((ext_vector_type(8))) _Float16 f16x8;
typedef __attribute__((ext_vector_type(16))) float f32x16;
typedef __attribute__((ext_vector_type(2))) float v2f;

__device__ __forceinline__ ushort bf16bits(float x) {
    __hip_bfloat16 h = __float2bfloat16(x);
    return *reinterpret_cast<ushort*>(&h);
}
__device__ __forceinline__ ushort f16bits(float x) {
    _Float16 h = (_Float16)x;
    return *reinterpret_cast<ushort*>(&h);
}

// ---------------- K1: fused prep ---------------------------------------------
// + new tail branch: wout^T transpose to f16 (16 blocks of 64x64 tiles)
__global__ __launch_bounds__(256) void k_prep(
        const float* __restrict__ fm0, const float* __restrict__ fm1,
        const float* __restrict__ fm2, const float* __restrict__ fm3,
        unsigned char* __restrict__ t0, unsigned char* __restrict__ t1,
        unsigned char* __restrict__ t2, unsigned char* __restrict__ t3,
        const float* __restrict__ wlin, __hip_bfloat16* __restrict__ wt,
        const float* __restrict__ inst, const float* __restrict__ anch,
        __hip_bfloat16* __restrict__ featB,
        const float* __restrict__ kp, const float* __restrict__ proj,
        float* __restrict__ pxy,
        const float* __restrict__ wout, ushort* __restrict__ woutT) {
    __shared__ ushort lds2[128 * 64];     // 16 KiB
    int b = blockIdx.x;
    int t = threadIdx.x;
    if (b < 1404) {
        const float* in; unsigned char* outp; int HW, chunks, lb;
        if (b < 1056)      { in = fm0; outp = t0; HW = 11264; chunks = 176; lb = b; }
        else if (b < 1320) { in = fm1; outp = t1; HW = 2816;  chunks = 44;  lb = b - 1056; }
        else if (b < 1386) { in = fm2; outp = t2; HW = 704;   chunks = 11;  lb = b - 1320; }
        else               { in = fm3; outp = t3; HW = 176;   chunks = 3;   lb = b - 1386; }
        int c = lb / chunks;
        int hw0 = (lb - c * chunks) * 64;
        int q = t & 15, eg = t >> 4;
        bool vld = (hw0 + q * 4 + 3) < HW;
        const float* srcq = in + (size_t)c * EMBED * HW + hw0 + q * 4;
        float4 vals[16];
        #pragma unroll
        for (int r = 0; r < 16; r++) {
            int e = 2 * eg + (r & 1) + 32 * (r >> 1);
            vals[r] = vld ? *(const float4*)(srcq + (size_t)e * HW)
                          : make_float4(0.f, 0.f, 0.f, 0.f);
        }
        #pragma unroll
        for (int rp = 0; rp < 8; rp++) {
            int ep = eg + 16 * rp;
            int s2 = (ep >> 1) & 62;
            float4 va = vals[2 * rp], vb = vals[2 * rp + 1];
            uint p0 = (uint)__builtin_amdgcn_cvt_pk_fp8_f32(va.x, vb.x, 0, false) & 0xffff;
            uint p1 = (uint)__builtin_amdgcn_cvt_pk_fp8_f32(va.y, vb.y, 0, false) & 0xffff;
            uint p2 = (uint)__builtin_amdgcn_cvt_pk_fp8_f32(va.z, vb.z, 0, false) & 0xffff;
            uint p3 = (uint)__builtin_amdgcn_cvt_pk_fp8_f32(va.w, vb.w, 0, false) & 0xffff;
            int col01 = (q * 4) ^ s2;
            int col23 = (q * 4 + 2) ^ s2;
            *reinterpret_cast<uint*>(&lds2[ep * 64 + col01]) = p0 | (p1 << 16);
            *reinterpret_cast<uint*>(&lds2[ep * 64 + col23]) = p2 | (p3 << 16);
        }
        __syncthreads();
        ushort* outb = reinterpret_cast<ushort*>(outp) + ((size_t)c * HW + hw0) * 128;
        #pragma unroll
        for (int r = 0; r < 8; r++) {
            int flat = r * 2048 + t * 8;          // byte index in chunk
            int hw = flat >> 8;
            int ep0 = (flat & 255) >> 1;          // 4*(t&31)
            if (hw0 + hw < HW) {
                ushort4 u;
                #pragma unroll
                for (int j = 0; j < 4; j++) {
                    int ep = ep0 + j;
                    int s2 = (ep >> 1) & 62;
                    u[j] = lds2[ep * 64 + (hw ^ s2)];
                }
                *reinterpret_cast<ushort4*>(outb + flat / 2) = u;
            }
        }
    } else if (b < 1560) {
        int b1 = b - 1404;
        int kt = b1 / 39, nt = b1 - kt * 39;
        int k0 = kt * 64, n0 = nt * 64;
        int grp = t >> 6, nn = t & 63;
        #pragma unroll
        for (int r = 0; r < 16; r++) {
            int kk = grp * 16 + r;
            lds2[kk * 65 + nn] = bf16bits(wlin[(size_t)(k0 + kk) * NWCOL + n0 + nn]);
        }
        __syncthreads();
        ushort* wtb = reinterpret_cast<ushort*>(wt);
        int kk2 = t & 63;
        #pragma unroll
        for (int r = 0; r < 16; r++) {
            int nn2 = grp * 16 + r;
            wtb[(size_t)(n0 + nn2) * EMBED + k0 + kk2] = lds2[kk2 * 65 + nn2];
        }
    } else if (b < 1785) {
        int base = (b - 1560) * 1024 + t * 4;
        float4 a = *(const float4*)&inst[base];
        float4 c = *(const float4*)&anch[base];
        ushort4 r;
        r.x = bf16bits(a.x + c.x); r.y = bf16bits(a.y + c.y);
        r.z = bf16bits(a.z + c.z); r.w = bf16bits(a.w + c.w);
        *reinterpret_cast<ushort4*>(reinterpret_cast<ushort*>(featB) + base) = r;
    } else if (b < 1792) {
        int base = 900 * EMBED + (b - 1785) * 1024 + t * 4;
        ushort4 z; z.x = z.y = z.z = z.w = 0;
        *reinterpret_cast<ushort4*>(reinterpret_cast<ushort*>(featB) + base) = z;
    } else if (b < 2067) {
        int i = (b - 1792) * 256 + t;
        if (i < NANC * NCAM * NPT) {
            int a = i / (NCAM * NPT);
            int r = i - a * (NCAM * NPT);
            int c = r / NPT;
            int p = r - c * NPT;
            const float* M = proj + c * 16;
            const float* k3 = kp + ((size_t)a * NPT + p) * 3;
            float kx = k3[0], ky = k3[1], kz = k3[2];
            float X = M[0] * kx + M[1] * ky + M[2] * kz + M[3];
            float Y = M[4] * kx + M[5] * ky + M[6] * kz + M[7];
            float Z = M[8] * kx + M[9] * ky + M[10] * kz + M[11];
            float invz = 1.f / fmaxf(Z, 1e-5f);
            pxy[(size_t)i * 2 + 0] = X * invz;
            pxy[(size_t)i * 2 + 1] = Y * invz;
        }
    } else {
        // wout^T -> f16, 64x64 tiles (4x4 grid)
        int b1 = b - 2067;
        int kt = b1 >> 2, nt = b1 & 3;
        int k0 = kt * 64, n0 = nt * 64;
        int grp = t >> 6, nn = t & 63;
        #pragma unroll
        for (int r = 0; r < 16; r++) {
            int kk = grp * 16 + r;
            lds2[kk * 65 + nn] = f16bits(wout[(size_t)(k0 + kk) * EMBED + n0 + nn]);
        }
        __syncthreads();
        int kk2 = t & 63;
        #pragma unroll
        for (int r = 0; r < 16; r++) {
            int nn2 = grp * 16 + r;
            woutT[(size_t)(n0 + nn2) * EMBED + k0 + kk2] = lds2[kk2 * 65 + nn2];
        }
    }
}

// ---------------- K2: logits GEMM via MFMA bf16, f16 output ------------------
#define MT 29
#define NT 78
__global__ __launch_bounds__(256) void k_gemm(const __hip_bfloat16* __restrict__ featB,
                                              const __hip_bfloat16* __restrict__ wt,
                                              const float* __restrict__ blin,
                                              _Float16* __restrict__ logits) {
    int wv = threadIdx.x >> 6, lane = threadIdx.x & 63;
    int idx = blockIdx.x * 4 + wv;
    if (idx >= MT * NT) return;
    int mt = idx % MT, nt = idx / MT;
    int m0 = mt * 32, n0 = nt * 32;
    int l31 = lane & 31;
    int khalf = (lane >> 5) * 8;
    const short* ap = reinterpret_cast<const short*>(featB) + (size_t)(m0 + l31) * EMBED + khalf;
    const short* bp = reinterpret_cast<const short*>(wt)    + (size_t)(n0 + l31) * EMBED + khalf;
    f32x16 acc = {};
    #pragma unroll 8
    for (int ki = 0; ki < 16; ki++) {
        bf16x8 a = *reinterpret_cast<const bf16x8*>(ap + ki * 16);
        bf16x8 bb = *reinterpret_cast<const bf16x8*>(bp + ki * 16);
        acc = __builtin_amdgcn_mfma_f32_32x32x16_bf16(a, bb, acc, 0, 0, 0);
    }
    float bias = blin[n0 + l31];
    int colg = n0 + l31;
    #pragma unroll
    for (int r = 0; r < 16; r++) {
        int row = (r & 3) + 8 * (r >> 2) + 4 * (lane >> 5);
        int grow = m0 + row;
        if (grow < NANC)
            logits[(size_t)grow * NWCOL + colg] = (_Float16)(acc[r] + bias);
    }
}

// ---------------- K3: softmax + compacted fp8 gather -------------------------
// Epilogue GEMV removed: writes fused (f16, softmax-denominator-rescaled) to
// workspace; K4 does the output projection via MFMA.
__global__ __launch_bounds__(512) void k_aggregate(const unsigned char* __restrict__ tAll,
                                                   const _Float16* __restrict__ logits,
                                                   const float* __restrict__ pxy,
                                                   _Float16* __restrict__ fusedH) {
    __shared__ float wT[GPS * WSTRIDE];    // 10496 B
    __shared__ float xyS[NCAM * NPT * 2];  // 624 B
    __shared__ float redS[8][EMBED];       // 8192 B
    __shared__ float rsS[GPS];             // 32 B
    __shared__ int4  eOff[MAXENT];         // 5632 B
    __shared__ float4 eW[MAXENT];          // 5632 B
    __shared__ int   eS[MAXENT];           // 1408 B
    __shared__ int   cntS;
    int a = blockIdx.x;
    int tid = threadIdx.x;
    int wave = tid >> 6;
    int lane = tid & 63;
    if (tid == 0) cntS = 0;
    for (int j = tid; j < NWCOL; j += 512)
        wT[(j & 7) * WSTRIDE + (j >> 3)] = (float)logits[(size_t)a * NWCOL + j];
    for (int j = tid; j < NCAM * NPT * 2; j += 512)
        xyS[j] = pxy[(size_t)a * NCAM * NPT * 2 + j];
    __syncthreads();
    // ---- softmax numerator: wave g owns group g; wT <- exp(x - m) ----
    {
        int g = wave;
        float m = -1e30f;
        for (int s = lane; s < NSAMP; s += 64) m = fmaxf(m, wT[g * WSTRIDE + s]);
        #pragma unroll
        for (int off = 32; off; off >>= 1) m = fmaxf(m, __shfl_xor(m, off));
        float ssum = 0.f;
        for (int s = lane; s < NSAMP; s += 64) {
            float e = __expf(wT[g * WSTRIDE + s] - m);
            wT[g * WSTRIDE + s] = e;
            ssum += e;
        }
        #pragma unroll
        for (int off = 32; off; off >>= 1) ssum += __shfl_xor(ssum, off);
        if (lane == 0) rsS[g] = 1.f / ssum;
    }
    // ---- sample precompute + compaction ----
    {
        bool valid = false; int4 o4; float4 w4;
        if (tid < NSAMP) {
            int c = tid / 52, rem = tid - c * 52;
            int l = rem / 13, p = rem - l * 13;
            float X = xyS[(c * NPT + p) * 2], Y = xyS[(c * NPT + p) * 2 + 1];
            int Wl = 176 >> l, Hl = 64 >> l;
            float scale = 0.25f / (float)(1 << l);
            float gx = fmaf(X, scale, -0.5f);
            float gy = fmaf(Y, scale, -0.5f);
            float x0f = floorf(gx), y0f = floorf(gy);
            float fx = gx - x0f, fy = gy - y0f;
            int x0 = (int)x0f, y0 = (int)y0f;
            int x1 = x0 + 1, y1 = y0 + 1;
            bool vx0 = (x0 >= 0) && (x0 < Wl);
            bool vx1 = (x1 >= 0) && (x1 < Wl);
            bool vy0 = (y0 >= 0) && (y0 < Hl);
            bool vy1 = (y1 >= 0) && (y1 < Hl);
            w4.x = (vx0 && vy0) ? (1.f - fx) * (1.f - fy) : 0.f;
            w4.y = (vx1 && vy0) ? fx * (1.f - fy) : 0.f;
            w4.z = (vx0 && vy1) ? (1.f - fx) * fy : 0.f;
            w4.w = (vx1 && vy1) ? fx * fy : 0.f;
            if (w4.x + w4.y + w4.z + w4.w > 0.f) {
                valid = true;
                int xc0 = min(max(x0, 0), Wl - 1), xc1 = min(max(x1, 0), Wl - 1);
                int yc0 = min(max(y0, 0), Hl - 1), yc1 = min(max(y1, 0), Hl - 1);
                const int lvlBase[4] = { FMOFF0, FMOFF1, FMOFF2, FMOFF3 };
                int cb = lvlBase[l] + c * (Wl * Hl) * EMBED;
                o4.x = cb + (yc0 * Wl + xc0) * EMBED;
                o4.y = cb + (yc0 * Wl + xc1) * EMBED;
                o4.z = cb + (yc1 * Wl + xc0) * EMBED;
                o4.w = cb + (yc1 * Wl + xc1) * EMBED;
            }
        }
        unsigned long long mask = __ballot(valid);
        int prefix = __popcll(mask & ((1ull << lane) - 1ull));
        int wcount = __popcll(mask);
        int basev = 0;
        if (lane == 0 && wcount) basev = atomicAdd(&cntS, wcount);
        basev = __shfl(basev, 0);
        if (valid) {
            int pos = basev + prefix;
            eOff[pos] = o4; eW[pos] = w4; eS[pos] = tid;
        }
    }
    __syncthreads();
    int cnt = cntS;
    int cnt_pad = (cnt + 31) & ~31;       // multiple of 32 -> steps even
    for (int j = cnt + tid; j < cnt_pad; j += 512) {
        eOff[j] = make_int4(0, 0, 0, 0);
        eW[j] = make_float4(0.f, 0.f, 0.f, 0.f);
        eS[j] = 0;
    }
    __syncthreads();
    // ---- phase B: half-wave dual-entry pipelined fp8 gather ----
    int half = lane >> 5;
    int hl = lane & 31;
    int ch0 = hl * 8;                     // byte offset of this lane's 8 channels
    int g = hl >> 2;                      // group of channels [ch0, ch0+8)
    float acc0 = 0.f, acc1 = 0.f, acc2 = 0.f, acc3 = 0.f;
    float acc4 = 0.f, acc5 = 0.f, acc6 = 0.f, acc7 = 0.f;
    auto consume = [&](const float4& w, int sIdx,
                       uint2 c0, uint2 c1, uint2 c2, uint2 c3) {
        float wg = wT[g * WSTRIDE + sIdx];
        float w0 = wg * w.x, w1 = wg * w.y, w2 = wg * w.z, w3 = wg * w.w;
        v2f p;
        p = __builtin_amdgcn_cvt_pk_f32_fp8(c0.x, false); acc0 = fmaf(w0, p.x, acc0); acc1 = fmaf(w0, p.y, acc1);
        p = __builtin_amdgcn_cvt_pk_f32_fp8(c0.x, true);  acc2 = fmaf(w0, p.x, acc2); acc3 = fmaf(w0, p.y, acc3);
        p = __builtin_amdgcn_cvt_pk_f32_fp8(c0.y, false); acc4 = fmaf(w0, p.x, acc4); acc5 = fmaf(w0, p.y, acc5);
        p = __builtin_amdgcn_cvt_pk_f32_fp8(c0.y, true);  acc6 = fmaf(w0, p.x, acc6); acc7 = fmaf(w0, p.y, acc7);
        p = __builtin_amdgcn_cvt_pk_f32_fp8(c1.x, false); acc0 = fmaf(w1, p.x, acc0); acc1 = fmaf(w1, p.y, acc1);
        p = __builtin_amdgcn_cvt_pk_f32_fp8(c1.x, true);  acc2 = fmaf(w1, p.x, acc2); acc3 = fmaf(w1, p.y, acc3);
        p = __builtin_amdgcn_cvt_pk_f32_fp8(c1.y, false); acc4 = fmaf(w1, p.x, acc4); acc5 = fmaf(w1, p.y, acc5);
        p = __builtin_amdgcn_cvt_pk_f32_fp8(c1.y, true);  acc6 = fmaf(w1, p.x, acc6); acc7 = fmaf(w1, p.y, acc7);
        p = __builtin_amdgcn_cvt_pk_f32_fp8(c2.x, false); acc0 = fmaf(w2, p.x, acc0); acc1 = fmaf(w2, p.y, acc1);
        p = __builtin_amdgcn_cvt_pk_f32_fp8(c2.x, true);  acc2 = fmaf(w2, p.x, acc2); acc3 = fmaf(w2, p.y, acc3);
        p = __builtin_amdgcn_cvt_pk_f32_fp8(c2.y, false); acc4 = fmaf(w2, p.x, acc4); acc5 = fmaf(w2, p.y, acc5);
        p = __builtin_amdgcn_cvt_pk_f32_fp8(c2.y, true);  acc6 = fmaf(w2, p.x, acc6); acc7 = fmaf(w2, p.y, acc7);
        p = __builtin_amdgcn_cvt_pk_f32_fp8(c3.x, false); acc0 = fmaf(w3, p.x, acc0); acc1 = fmaf(w3, p.y, acc1);
        p = __builtin_amdgcn_cvt_pk_f32_fp8(c3.x, true);  acc2 = fmaf(w3, p.x, acc2); acc3 = fmaf(w3, p.y, acc3);
        p = __builtin_amdgcn_cvt_pk_f32_fp8(c3.y, false); acc4 = fmaf(w3, p.x, acc4); acc5 = fmaf(w3, p.y, acc5);
        p = __builtin_amdgcn_cvt_pk_f32_fp8(c3.y, true);  acc6 = fmaf(w3, p.x, acc6); acc7 = fmaf(w3, p.y, acc7);
    };
    int steps = cnt_pad >> 4;             // 16 entries consumed per step (8 waves x 2)
    if (steps > 0) {
        int ei = wave * 2 + half;
        int4 oA = eOff[ei]; float4 wA = eW[ei]; int sA = eS[ei];
        uint2 vA0 = *(const uint2*)(tAll + oA.x + ch0);
        uint2 vA1 = *(const uint2*)(tAll + oA.y + ch0);
        uint2 vA2 = *(const uint2*)(tAll + oA.z + ch0);
        uint2 vA3 = *(const uint2*)(tAll + oA.w + ch0);
        for (int it = 0; it < steps; it += 2) {
            int ej = ei + 16;
            int4 oB = eOff[ej]; float4 wB = eW[ej]; int sB = eS[ej];
            uint2 vB0 = *(const uint2*)(tAll + oB.x + ch0);
            uint2 vB1 = *(const uint2*)(tAll + oB.y + ch0);
            uint2 vB2 = *(const uint2*)(tAll + oB.z + ch0);
            uint2 vB3 = *(const uint2*)(tAll + oB.w + ch0);
            consume(wA, sA, vA0, vA1, vA2, vA3);
            ei = ej + 16;
            if (it + 2 < steps) {
                oA = eOff[ei]; wA = eW[ei]; sA = eS[ei];
                vA0 = *(const uint2*)(tAll + oA.x + ch0);
                vA1 = *(const uint2*)(tAll + oA.y + ch0);
                vA2 = *(const uint2*)(tAll + oA.z + ch0);
                vA3 = *(const uint2*)(tAll + oA.w + ch0);
            }
            consume(wB, sB, vB0, vB1, vB2, vB3);
        }
    }
    // combine the two half-waves (same channels, disjoint entries)
    acc0 += __shfl_xor(acc0, 32); acc1 += __shfl_xor(acc1, 32);
    acc2 += __shfl_xor(acc2, 32); acc3 += __shfl_xor(acc3, 32);
    acc4 += __shfl_xor(acc4, 32); acc5 += __shfl_xor(acc5, 32);
    acc6 += __shfl_xor(acc6, 32); acc7 += __shfl_xor(acc7, 32);
    if (half == 0) {
        redS[wave][ch0 + 0] = acc0; redS[wave][ch0 + 1] = acc1;
        redS[wave][ch0 + 2] = acc2; redS[wave][ch0 + 3] = acc3;
        redS[wave][ch0 + 4] = acc4; redS[wave][ch0 + 5] = acc5;
        redS[wave][ch0 + 6] = acc6; redS[wave][ch0 + 7] = acc7;
    }
    __syncthreads();
    // ---- channel sum + softmax denom rescale -> f16 fused row ----
    if (tid < EMBED) {
        int col = tid;
        float s = redS[0][col] + redS[1][col] + redS[2][col] + redS[3][col]
                + redS[4][col] + redS[5][col] + redS[6][col] + redS[7][col];
        fusedH[(size_t)a * EMBED + col] = (_Float16)(s * rsS[col >> 5]);
    }
}

// ---------------- K4: output projection MFMA f16 -----------------------------
// out[900x256] = fused[900x256] @ wout[256x256] + bout + inst
#define MT2 29
#define NT2 8
__global__ __launch_bounds__(256) void k_out(const _Float16* __restrict__ fusedH,
                                             const _Float16* __restrict__ woutT,
                                             const float* __restrict__ bout,
                                             const float* __restrict__ inst,
                                             float* __restrict__ out) {
    int wv = threadIdx.x >> 6, lane = threadIdx.x & 63;
    int idx = blockIdx.x * 4 + wv;
    if (idx >= MT2 * NT2) return;
    int mt = idx % MT2, nt = idx / MT2;
    int m0 = mt * 32, n0 = nt * 32;
    int l31 = lane & 31;
    int khalf = (lane >> 5) * 8;
    const _Float16* ap = fusedH + (size_t)(m0 + l31) * EMBED + khalf;
    const _Float16* bp = woutT  + (size_t)(n0 + l31) * EMBED + khalf;
    f32x16 acc = {};
    #pragma unroll 8
    for (int ki = 0; ki < 16; ki++) {
        f16x8 a  = *reinterpret_cast<const f16x8*>(ap + ki * 16);
        f16x8 bb = *reinterpret_cast<const f16x8*>(bp + ki * 16);
        acc = __builtin_amdgcn_mfma_f32_32x32x16_f16(a, bb, acc, 0, 0, 0);
    }
    int colg = n0 + l31;
    float bias = bout[colg];
    #pragma unroll
    for (int r = 0; r < 16; r++) {
        int row = (r & 3) + 8 * (r >> 2) + 4 * (lane >> 5);
        int grow = m0 + row;
        if (grow < NANC)
            out[(size_t)grow * EMBED + colg] = acc[r] + bias + inst[(size_t)grow * EMBED + colg];
    }
}

extern "C" void kernel_launch(void* const* d_in, const int* in_sizes, int n_in,
                              void* d_out, int out_size, void* d_ws, size_t ws_size,
                              hipStream_t stream) {
    const float* inst = (const float*)d_in[0];
    const float* anch = (const float*)d_in[1];
    const float* kp   = (const float*)d_in[2];
    const float* fm0  = (const float*)d_in[3];
    const float* fm1  = (const float*)d_in[4];
    const float* fm2  = (const float*)d_in[5];
    const float* fm3  = (const float*)d_in[6];
    const float* proj = (const float*)d_in[7];
    const float* wlin = (const float*)d_in[9];
    const float* blin = (const float*)d_in[10];
    const float* wout = (const float*)d_in[11];
    const float* bout = (const float*)d_in[12];
    float* out = (float*)d_out;

    char* ws = (char*)d_ws;
    size_t off = 0;
    auto alloc = [&](size_t bytes) -> void* {
        void* p = ws + off;
        off = (off + bytes + 255) & ~(size_t)255;
        return p;
    };
    unsigned char* tAll = (unsigned char*)alloc((size_t)TALL_BYTES);
    unsigned char* t0 = tAll + FMOFF0;
    unsigned char* t1 = tAll + FMOFF1;
    unsigned char* t2 = tAll + FMOFF2;
    unsigned char* t3 = tAll + FMOFF3;
    __hip_bfloat16* wt    = (__hip_bfloat16*)alloc((size_t)NWCOL * EMBED * 2);
    __hip_bfloat16* featB = (__hip_bfloat16*)alloc((size_t)MPAD * EMBED * 2);
    _Float16* logits = (_Float16*)alloc((size_t)NANC * NWCOL * 2);
    float* pxy       = (float*)alloc((size_t)NANC * NCAM * NPT * 2 * 4);
    _Float16* fusedH = (_Float16*)alloc((size_t)MPAD * EMBED * 2);
    ushort* woutT    = (ushort*)alloc((size_t)EMBED * EMBED * 2);

    k_prep<<<dim3(2083), 256, 0, stream>>>(fm0, fm1, fm2, fm3, t0, t1, t2, t3,
                                           wlin, wt, inst, anch, featB, kp, proj, pxy,
                                           wout, woutT);
    k_gemm<<<dim3((MT * NT + 3) / 4), 256, 0, stream>>>(featB, wt, blin, logits);
    k_aggregate<<<dim3(NANC), 512, 0, stream>>>(tAll, logits, pxy, fusedH);
    k_out<<<dim3((MT2 * NT2 + 3) / 4), 256, 0, stream>>>(fusedH, (const _Float16*)woutT,
                                                         bout, inst, out);
}